// Round 1
// baseline (203.772 us; speedup 1.0000x reference)
//
#include <hip/hip_runtime.h>

// ---------------- workspace layout (uint32 units from ws base) --------------
#define WS_ACC_POS   0          // [96] uint  pos count per group g = s*32+b
#define WS_ACC_NEG   96         // [96] uint  neg count
#define WS_ACC_OBJ   192        // [96] float sum obj_loss over pos
#define WS_ACC_CLS   288        // [96] float sum ce over pos
#define WS_ACC_LOC   384        // [96] float sum smoothl1 over pos
#define WS_ACC_ABOVE 480        // [96] float sum of neg losses in bins > tie1
#define WS_ACC_TIE1  576        // [96] int   level-1 tie bin (INT_MAX if k==0)
#define WS_ACC_R1    672        // [96] int   rank remaining within tie bin
#define WS_HIST1     768        // [96][2048] uint
#define WS_HIST2C    197376     // [96][4096] uint
#define WS_HIST2S    590592     // [96][4096] float
#define WS_NEGPAT    983808     // [2064384] uint  per-anchor pattern (0xFFFFFFFF = not neg)
#define WS_TOTAL_U32 3048192

#define PATBASE1 1572864        // 32*49152
#define PATBASE2 1966080        // + 32*12288

__device__ __forceinline__ float getc(const float4 v, int i){
  return i==0?v.x : i==1?v.y : i==2?v.z : v.w;
}
__device__ __forceinline__ float sl1f(float d){
  float ad = fabsf(d); return ad < 1.f ? 0.5f*d*d : ad - 0.5f;
}

// ---------------------------------------------------------------------------
// K1: per-anchor compute. grid (16,3,32): chunk, scale, batch. 256 thr.
// Each block: 1024 hw locations x 3 anchors. Each thread: 4 consecutive hw.
// ---------------------------------------------------------------------------
__global__ __launch_bounds__(256) void k_main(
    const float* __restrict__ p0, const float* __restrict__ p1, const float* __restrict__ p2,
    const float* __restrict__ gtb, const int* __restrict__ gtl,
    unsigned int* __restrict__ ws)
{
  const int chunk = blockIdx.x, s = blockIdx.y, b = blockIdx.z;
  int H; const float* p; int patBase;
  if (s==0){ H=128; p=p0; patBase=0; }
  else if (s==1){ H=64; p=p1; patBase=PATBASE1; }
  else { H=32; p=p2; patBase=PATBASE2; }
  const int W = H, HW = H*W;
  if (chunk >= (HW>>10)) return;
  const int g = s*32 + b;
  const float stride = 512.0f/(float)H;

  __shared__ float4 sBox[52];
  __shared__ float  sArea[52], sGx[52], sGy[52], sGw[52], sGh[52];
  __shared__ int    sLbl[52];
  __shared__ int    sNk;
  __shared__ unsigned int sHist[2048];

  const int tid = threadIdx.x;

  // ---- GT load + spatial prune + order-preserving compaction (wave 0) ----
  {
    const int rowsPerChunk = 1024/W;
    const int ymin = chunk*rowsPerChunk, ymax = ymin + rowsPerChunk - 1;
    const float by1 = (ymin+0.5f)*stride - 2.0f*stride;   // min anchor y1 in block
    const float by2 = (ymax+0.5f)*stride + 2.0f*stride;   // max anchor y2
    const float bx1 = 0.5f*stride - 2.0f*stride;
    const float bx2 = ((float)W-0.5f)*stride + 2.0f*stride;
    if (tid < 64){
      bool keep=false; float4 gb=make_float4(0,0,0,0); int lbl=0;
      if (tid < 50){
        gb  = *(const float4*)(gtb + ((size_t)b*50 + tid)*4);
        lbl = gtl[b*50 + tid];
        float ovy = fminf(by2, gb.w) - fmaxf(by1, gb.y);
        float ovx = fminf(bx2, gb.z) - fmaxf(bx1, gb.x);
        keep = (ovy > 0.f) && (ovx > 0.f);
      }
      unsigned long long m = __ballot(keep);
      if (keep){
        int idx = __popcll(m & ((1ull<<tid)-1ull));
        sBox[idx]=gb;
        sArea[idx]=(gb.z-gb.x)*(gb.w-gb.y);
        sGx[idx]=(gb.x+gb.z)*0.5f;  sGy[idx]=(gb.y+gb.w)*0.5f;
        sGw[idx]=fmaxf(gb.z-gb.x,1e-6f); sGh[idx]=fmaxf(gb.w-gb.y,1e-6f);
        sLbl[idx]=lbl;
      }
      if (tid==0) sNk = __popcll(m);
    }
  }
  for (int h=tid; h<2048; h+=256) sHist[h]=0u;
  __syncthreads();

  const int nk = sNk;
  const int hw0 = chunk*1024 + tid*4;
  const int y = hw0 / W, x0 = hw0 - y*W;        // 4 positions share a row (W%4==0)
  const float cy = ((float)y + 0.5f)*stride;

  int accPos=0, accNeg=0;
  float accObj=0.f, accCls=0.f, accLoc=0.f;

  #pragma unroll
  for (int a=0;a<3;a++){
    const float half  = (a==0?1.0f : a==1?1.5f : 2.0f)*stride;
    const float aw    = 2.0f*half;              // exact == (cx+half)-(cx-half)
    const float areaA = aw*aw;
    const float ay1 = cy-half, ay2 = cy+half;

    float4 q[8];
    const float* pb = p + ((size_t)(b*24 + a*8))*HW + hw0;
    #pragma unroll
    for (int j=0;j<8;j++) q[j] = *(const float4*)(pb + (size_t)j*HW);

    float ax1[4], ax2[4], cxv[4];
    #pragma unroll
    for (int i=0;i<4;i++){
      cxv[i] = ((float)(x0+i) + 0.5f)*stride;
      ax1[i] = cxv[i]-half; ax2[i] = cxv[i]+half;
    }
    float bi[4]={0.f,0.f,0.f,0.f}, bu[4]={1e-9f,1e-9f,1e-9f,1e-9f};
    int bj[4]={0,0,0,0};
    for (int j=0;j<nk;j++){
      const float4 gb = sBox[j];
      const float ab  = areaA + sArea[j];
      const float iy1 = fmaxf(ay1, gb.y), iy2 = fminf(ay2, gb.w);
      const float ih  = fmaxf(iy2-iy1, 0.f);
      #pragma unroll
      for (int i=0;i<4;i++){
        const float ix1 = fmaxf(ax1[i], gb.x), ix2 = fminf(ax2[i], gb.z);
        const float iw  = fmaxf(ix2-ix1, 0.f);
        const float inter = iw*ih;
        const float un = ab - inter;            // union >= areaA >= 64 > 1e-9
        if (inter*bu[i] > bi[i]*un){ bi[i]=inter; bu[i]=un; bj[i]=j; }
      }
    }
    unsigned int pats[4];
    #pragma unroll
    for (int i=0;i<4;i++){
      const float bestIou = bi[i]/bu[i];
      const bool pos = bestIou >= 0.5f;
      const bool neg = bestIou < 0.3f;
      const float xo = getc(q[4], i);
      float objl = fmaxf(xo,0.f) - (pos ? xo : 0.f)
                 + __logf(1.f + __expf(-fabsf(xo)));
      objl = fmaxf(objl, 0.f);                  // keep sign bit 0 for radix bins
      if (pos){
        accPos++; accObj += objl;
        const int jb = bj[i];
        const float c0=getc(q[5],i), c1=getc(q[6],i), c2=getc(q[7],i);
        const float mm = fmaxf(fmaxf(c0,c1),c2);
        const float lse = mm + __logf(__expf(c0-mm)+__expf(c1-mm)+__expf(c2-mm));
        const int t = max(sLbl[jb]-1, 0);
        const float ct = (t==0)?c0 : (t==1)?c1 : c2;
        accCls += lse - ct;
        const float tx = (sGx[jb]-cxv[i])/aw;
        const float ty = (sGy[jb]-cy )/aw;      // ah == aw (square anchors)
        const float tw = __logf(sGw[jb]/aw);
        const float th = __logf(sGh[jb]/aw);
        accLoc += sl1f(getc(q[0],i)-tx) + sl1f(getc(q[1],i)-ty)
                + sl1f(getc(q[2],i)-tw) + sl1f(getc(q[3],i)-th);
      }
      unsigned int pat = 0xFFFFFFFFu;
      if (neg){
        accNeg++;
        pat = __float_as_uint(objl);
        atomicAdd(&sHist[pat>>20], 1u);
      }
      pats[i] = pat;
    }
    *(uint4*)(ws + WS_NEGPAT + patBase + (size_t)(b*3 + a)*HW + hw0)
        = make_uint4(pats[0],pats[1],pats[2],pats[3]);
  }

  // ---- block reductions -> global group accumulators ----
  #pragma unroll
  for (int o=32;o;o>>=1){
    accPos += __shfl_down(accPos,o,64);
    accNeg += __shfl_down(accNeg,o,64);
    accObj += __shfl_down(accObj,o,64);
    accCls += __shfl_down(accCls,o,64);
    accLoc += __shfl_down(accLoc,o,64);
  }
  if ((tid & 63)==0){
    float* wf = (float*)ws;
    atomicAdd(&ws[WS_ACC_POS+g], (unsigned int)accPos);
    atomicAdd(&ws[WS_ACC_NEG+g], (unsigned int)accNeg);
    atomicAdd(&wf[WS_ACC_OBJ+g], accObj);
    atomicAdd(&wf[WS_ACC_CLS+g], accCls);
    atomicAdd(&wf[WS_ACC_LOC+g], accLoc);
  }
  __syncthreads();
  for (int h=tid; h<2048; h+=256){
    unsigned int v = sHist[h];
    if (v) atomicAdd(&ws[WS_HIST1 + g*2048 + h], v);
  }
}

// ---------------------------------------------------------------------------
// K2: per group find level-1 tie bin. 96 blocks x 256 thr.
// ---------------------------------------------------------------------------
__global__ __launch_bounds__(256) void k_sel1(unsigned int* __restrict__ ws){
  const int g = blockIdx.x, tid = threadIdx.x;
  const int pos  = (int)ws[WS_ACC_POS+g];
  const int negc = (int)ws[WS_ACC_NEG+g];
  const int k = min(3*pos, negc);
  const unsigned int* h1 = ws + WS_HIST1 + g*2048;
  __shared__ unsigned int part[256];
  unsigned int sm=0;
  #pragma unroll
  for (int i=0;i<8;i++) sm += h1[tid*8+i];
  part[tid]=sm; __syncthreads();
  if (tid==0){
    int tie = 0x7FFFFFFF, r1 = 0;
    if (k > 0){
      unsigned int cum=0; int t=255;
      for (; t>0; t--){ if (cum + part[t] >= (unsigned)k) break; cum += part[t]; }
      for (int bin=t*8+7; bin>=t*8; bin--){
        unsigned int c = h1[bin];
        if (cum + c >= (unsigned)k){ tie = bin; r1 = k - (int)cum; break; }
        cum += c;
      }
    }
    ((int*)ws)[WS_ACC_TIE1+g] = tie;
    ((int*)ws)[WS_ACC_R1 +g]  = r1;
  }
}

// ---------------------------------------------------------------------------
// K3: sum above tie bin + level-2 histogram. grid (16,3,32) x 256 thr.
// ---------------------------------------------------------------------------
__global__ __launch_bounds__(256) void k_pass2(unsigned int* __restrict__ ws){
  const int chunk = blockIdx.x, s = blockIdx.y, b = blockIdx.z;
  int H, patBase;
  if (s==0){ H=128; patBase=0; }
  else if (s==1){ H=64; patBase=PATBASE1; }
  else { H=32; patBase=PATBASE2; }
  const int HW = H*H;
  if (chunk >= (HW>>10)) return;
  const int g = s*32 + b, tid = threadIdx.x;
  const int tie1 = ((const int*)ws)[WS_ACC_TIE1+g];
  unsigned int* h2c = ws + WS_HIST2C + g*4096;
  float* h2s = (float*)ws + WS_HIST2S + g*4096;
  const unsigned int* np = ws + WS_NEGPAT + patBase + (size_t)b*3*HW;
  float localSum = 0.f;
  #pragma unroll
  for (int a=0;a<3;a++){
    const uint4 v = *(const uint4*)(np + a*HW + chunk*1024 + tid*4);
    unsigned int u[4] = {v.x, v.y, v.z, v.w};
    #pragma unroll
    for (int i=0;i<4;i++){
      const unsigned int uu = u[i];
      if (uu != 0xFFFFFFFFu){
        const int bin = (int)(uu>>20);
        if (bin > tie1) localSum += __uint_as_float(uu);
        else if (bin == tie1){
          atomicAdd(&h2c[(uu>>8)&0xFFFu], 1u);
          atomicAdd(&h2s[(uu>>8)&0xFFFu], __uint_as_float(uu));
        }
      }
    }
  }
  #pragma unroll
  for (int o=32;o;o>>=1) localSum += __shfl_down(localSum,o,64);
  if ((tid&63)==0) atomicAdd(&((float*)ws)[WS_ACC_ABOVE+g], localSum);
}

// ---------------------------------------------------------------------------
// K4: finish selection, compute group losses, reduce to 4 outputs.
// ---------------------------------------------------------------------------
__global__ __launch_bounds__(256) void k_final(unsigned int* __restrict__ ws,
                                               float* __restrict__ out){
  const int g = blockIdx.x, tid = threadIdx.x;
  float* wf = (float*)ws;
  const int pos  = (int)ws[WS_ACC_POS+g];
  const int negc = (int)ws[WS_ACC_NEG+g];
  const int k = min(3*pos, negc);
  const int tie1 = ((int*)ws)[WS_ACC_TIE1+g];
  const int r1   = ((int*)ws)[WS_ACC_R1 +g];
  const unsigned int* h2c = ws + WS_HIST2C + g*4096;
  const float* h2s = wf + WS_HIST2S + g*4096;
  __shared__ unsigned int pc[256];
  __shared__ float ps[256];
  unsigned int c=0; float smv=0.f;
  #pragma unroll
  for (int i=0;i<16;i++){ c += h2c[tid*16+i]; smv += h2s[tid*16+i]; }
  pc[tid]=c; ps[tid]=smv; __syncthreads();
  if (tid==0){
    float selSum = 0.f;
    if (k > 0){
      const float above = wf[WS_ACC_ABOVE+g];
      unsigned int cum=0; float sacc=0.f; int t=255;
      for (; t>0; t--){ if (cum + pc[t] >= (unsigned)r1) break; cum += pc[t]; sacc += ps[t]; }
      for (int bin=t*16+15; bin>=t*16; bin--){
        unsigned int cc = h2c[bin];
        if (cum + cc >= (unsigned)r1){
          const int need = r1 - (int)cum;
          const float T = __uint_as_float(((unsigned)tie1<<20)|((unsigned)bin<<8));
          selSum = above + sacc + (float)need * T;
          break;
        }
        cum += cc; sacc += h2s[bin];
      }
    }
    const int cObj = pos + k;
    const float lo = (cObj>0) ? (wf[WS_ACC_OBJ+g] + selSum)/(float)cObj : 0.f;
    const float lc = (pos>0)  ? wf[WS_ACC_CLS+g]/(float)pos            : 0.f;
    const float ll = (pos>0)  ? wf[WS_ACC_LOC+g]/(float)(4*pos)        : 0.f;
    const float invB = 1.f/32.f;
    atomicAdd(out+0, (1.0f*lo + 1.0f*lc + 2.0f*ll)*invB);
    atomicAdd(out+1, lo*invB);
    atomicAdd(out+2, lc*invB);
    atomicAdd(out+3, ll*invB);
  }
}

// ---------------------------------------------------------------------------
extern "C" void kernel_launch(void* const* d_in, const int* in_sizes, int n_in,
                              void* d_out, int out_size, void* d_ws, size_t ws_size,
                              hipStream_t stream){
  if (ws_size < (size_t)WS_TOTAL_U32*4) return;   // defensive: never write OOB
  const float* p0  = (const float*)d_in[0];
  const float* p1  = (const float*)d_in[1];
  const float* p2  = (const float*)d_in[2];
  const float* gtb = (const float*)d_in[6];
  const int*   gtl = (const int*)d_in[7];
  unsigned int* ws = (unsigned int*)d_ws;
  float* out = (float*)d_out;

  hipMemsetAsync(d_ws, 0, (size_t)WS_NEGPAT*4, stream);   // accums + hist1 + hist2
  hipMemsetAsync(d_out, 0, 4*sizeof(float), stream);

  dim3 gMain(16,3,32);
  hipLaunchKernelGGL(k_main,  gMain,    dim3(256), 0, stream, p0,p1,p2,gtb,gtl,ws);
  hipLaunchKernelGGL(k_sel1,  dim3(96), dim3(256), 0, stream, ws);
  hipLaunchKernelGGL(k_pass2, gMain,    dim3(256), 0, stream, ws);
  hipLaunchKernelGGL(k_final, dim3(96), dim3(256), 0, stream, ws, out);
}

// Round 2
// 132.214 us; speedup vs baseline: 1.5412x; 1.5412x over previous
//
#include <hip/hip_runtime.h>

// ---------------- workspace layout (uint32 units from ws base) --------------
#define WS_ACC_POS   0          // [96] uint  pos count per group g = s*32+b
#define WS_ACC_NEG   96         // [96] uint  neg count
#define WS_ACC_OBJ   192        // [96] float sum obj_loss over pos
#define WS_ACC_CLS   288        // [96] float sum ce over pos
#define WS_ACC_LOC   384        // [96] float sum smoothl1 over pos
#define WS_HIST1     512        // [96][2048] uint (level-1 counts)
#define WS_NEGPAT    197120     // [2064384] uint (0xFFFFFFFF = not neg)
#define PB1          1572864    // 32*3*16384
#define PB2          1966080    // + 32*3*4096
#define WS_TOTAL_U32 2261504

__device__ __forceinline__ float sl1f(float d){
  float ad = fabsf(d); return ad < 1.f ? 0.5f*d*d : ad - 0.5f;
}

// ---------------------------------------------------------------------------
// K1: per-anchor compute. Flat grid of 2688 blocks x 256 thr, 1 hw/thread.
//   ids [0,2048): s=0 (H=128, 64 chunks x 32 batch)
//   ids [2048,2560): s=1 (H=64, 16 chunks x 32)
//   ids [2560,2688): s=2 (H=32, 4 chunks x 32)
// ---------------------------------------------------------------------------
__global__ __launch_bounds__(256) void k_main(
    const float* __restrict__ p0, const float* __restrict__ p1, const float* __restrict__ p2,
    const float* __restrict__ gtb, const int* __restrict__ gtl,
    unsigned int* __restrict__ ws)
{
  const int id = blockIdx.x;
  int s, bIm, chunk, H, lw; const float* p; int patBase;
  if (id < 2048){ s=0; H=128; lw=7; chunk=id>>5;          bIm=id&31;          p=p0; patBase=0;   }
  else if (id < 2560){ s=1; H=64; lw=6; chunk=(id-2048)>>5; bIm=(id-2048)&31; p=p1; patBase=PB1; }
  else {              s=2; H=32; lw=5; chunk=(id-2560)>>5; bIm=(id-2560)&31;  p=p2; patBase=PB2; }
  const int W = H, HW = H*W;
  const float stride = 512.0f/(float)H;
  const int g = s*32 + bIm;
  const int tid = threadIdx.x;

  __shared__ float4 sBox[52];
  __shared__ float  sArea[52], sGx[52], sGy[52], sGw[52], sGh[52];
  __shared__ int    sLbl[52];
  __shared__ int    sNk;
  __shared__ unsigned int sHist[2048];
  __shared__ float  sRF[3][4];
  __shared__ unsigned int sRU[2][4];

  // ---- GT load + y-band prune + order-preserving compaction (wave 0) ----
  if (tid < 64){
    const int ymin = (chunk*256)>>lw;
    const int rowc = 256>>lw;
    const float by1 = ((float)ymin+0.5f)*stride - 2.0f*stride;
    const float by2 = ((float)(ymin+rowc-1)+0.5f)*stride + 2.0f*stride;
    bool keep=false; float4 gb=make_float4(0,0,0,0); int lbl=0;
    if (tid < 50){
      gb  = *(const float4*)(gtb + ((size_t)bIm*50 + tid)*4);
      lbl = gtl[bIm*50 + tid];
      keep = (fminf(by2, gb.w) - fmaxf(by1, gb.y)) > 0.f;
    }
    unsigned long long m = __ballot(keep);
    if (keep){
      int idx = __popcll(m & ((1ull<<tid)-1ull));
      sBox[idx]=gb;
      sArea[idx]=(gb.z-gb.x)*(gb.w-gb.y);
      sGx[idx]=(gb.x+gb.z)*0.5f;  sGy[idx]=(gb.y+gb.w)*0.5f;
      sGw[idx]=fmaxf(gb.z-gb.x,1e-6f); sGh[idx]=fmaxf(gb.w-gb.y,1e-6f);
      sLbl[idx]=lbl;
    }
    if (tid==0) sNk = __popcll(m);
  }
  for (int h=tid; h<2048; h+=256) sHist[h]=0u;
  __syncthreads();

  const int nk = sNk;
  const int hw = chunk*256 + tid;
  const int y = hw>>lw, x = hw&(W-1);
  const float cx = ((float)x+0.5f)*stride, cy = ((float)y+0.5f)*stride;

  float q[24];
  {
    const float* pb = p + (size_t)bIm*24*HW + hw;
    #pragma unroll
    for (int c=0;c<24;c++) q[c] = pb[(size_t)c*HW];
  }

  float half[3]; half[0]=stride; half[1]=1.5f*stride; half[2]=2.0f*stride;
  float areaA[3], bi[3], bu[3]; int bj[3];
  #pragma unroll
  for (int a=0;a<3;a++){
    const float aw = 2.0f*half[a];
    areaA[a]=aw*aw; bi[a]=0.f; bu[a]=1e-9f; bj[a]=0;
  }
  for (int j=0;j<nk;j++){
    const float4 gb = sBox[j];
    const float ar  = sArea[j];
    #pragma unroll
    for (int a=0;a<3;a++){
      const float iy1 = fmaxf(cy-half[a], gb.y), iy2 = fminf(cy+half[a], gb.w);
      const float ih  = fmaxf(iy2-iy1, 0.f);
      const float ix1 = fmaxf(cx-half[a], gb.x), ix2 = fminf(cx+half[a], gb.z);
      const float iw  = fmaxf(ix2-ix1, 0.f);
      const float inter = iw*ih;
      const float un = areaA[a] + ar - inter;   // >= 64 > 0
      if (inter*bu[a] > bi[a]*un){ bi[a]=inter; bu[a]=un; bj[a]=j; }
    }
  }

  int accPos=0, accNeg=0;
  float accObj=0.f, accCls=0.f, accLoc=0.f;
  #pragma unroll
  for (int a=0;a<3;a++){
    const float aw = 2.0f*half[a];
    const float bestIou = bi[a]/bu[a];
    const bool pos = bestIou >= 0.5f;
    const bool neg = bestIou < 0.3f;
    const float xo = q[a*8+4];
    float objl = fmaxf(xo,0.f) - (pos ? xo : 0.f)
               + __logf(1.f + __expf(-fabsf(xo)));
    objl = fmaxf(objl, 0.f);                    // sign bit 0 for radix bins
    if (pos){
      accPos++; accObj += objl;
      const int jb = bj[a];
      const float c0=q[a*8+5], c1=q[a*8+6], c2=q[a*8+7];
      const float mm = fmaxf(fmaxf(c0,c1),c2);
      const float lse = mm + __logf(__expf(c0-mm)+__expf(c1-mm)+__expf(c2-mm));
      const int t = max(sLbl[jb]-1, 0);
      const float ct = (t==0)?c0 : (t==1)?c1 : c2;
      accCls += lse - ct;
      const float tx = (sGx[jb]-cx)/aw;
      const float ty = (sGy[jb]-cy)/aw;         // ah == aw (square anchors)
      const float tw = __logf(sGw[jb]/aw);
      const float th = __logf(sGh[jb]/aw);
      accLoc += sl1f(q[a*8+0]-tx) + sl1f(q[a*8+1]-ty)
              + sl1f(q[a*8+2]-tw) + sl1f(q[a*8+3]-th);
    }
    unsigned int pat = 0xFFFFFFFFu;
    if (neg){
      accNeg++;
      pat = __float_as_uint(objl);
      atomicAdd(&sHist[pat>>20], 1u);
    }
    ws[WS_NEGPAT + patBase + ((size_t)bIm*3 + a)*HW + hw] = pat;
  }

  // ---- block reductions ----
  #pragma unroll
  for (int o=32;o;o>>=1){
    accPos += __shfl_down(accPos,o,64);
    accNeg += __shfl_down(accNeg,o,64);
    accObj += __shfl_down(accObj,o,64);
    accCls += __shfl_down(accCls,o,64);
    accLoc += __shfl_down(accLoc,o,64);
  }
  if ((tid & 63)==0){
    const int w = tid>>6;
    sRU[0][w]=(unsigned)accPos; sRU[1][w]=(unsigned)accNeg;
    sRF[0][w]=accObj; sRF[1][w]=accCls; sRF[2][w]=accLoc;
  }
  __syncthreads();
  if (tid==0){
    float* wf = (float*)ws;
    unsigned pc=0, nc=0; float ob=0,cl=0,lc=0;
    #pragma unroll
    for (int w=0;w<4;w++){ pc+=sRU[0][w]; nc+=sRU[1][w]; ob+=sRF[0][w]; cl+=sRF[1][w]; lc+=sRF[2][w]; }
    if (pc) atomicAdd(&ws[WS_ACC_POS+g], pc);
    if (nc) atomicAdd(&ws[WS_ACC_NEG+g], nc);
    if (ob!=0.f) atomicAdd(&wf[WS_ACC_OBJ+g], ob);
    if (cl!=0.f) atomicAdd(&wf[WS_ACC_CLS+g], cl);
    if (lc!=0.f) atomicAdd(&wf[WS_ACC_LOC+g], lc);
  }
  for (int h=tid; h<2048; h+=256){
    unsigned int v = sHist[h];
    if (v) atomicAdd(&ws[WS_HIST1 + g*2048 + h], v);
  }
}

// ---------------------------------------------------------------------------
// wave-level suffix-select: find bin where cumulative count from the top
// reaches `target`. Executed by lanes tid<64. scC[256] = per-super counts
// (bps bins per super, supers-per-lane = 4). Writes *sTie, *sR (= residual
// rank within tie bin, >=1) from the unique hitting lane.
// ---------------------------------------------------------------------------
__device__ __forceinline__ void wave_suffix_find(
    const unsigned int* __restrict__ binsLDS, const unsigned int* __restrict__ scC,
    int bps, unsigned int target, int* sTie, int* sR, int lane)
{
  const unsigned int c4 = scC[4*lane]+scC[4*lane+1]+scC[4*lane+2]+scC[4*lane+3];
  unsigned int incl = c4;
  #pragma unroll
  for (int off=1; off<64; off<<=1){
    unsigned int yv = __shfl_down(incl, off, 64);
    if (lane+off < 64) incl += yv;
  }
  const unsigned int excl = incl - c4;
  if (excl < target && incl >= target){       // unique lane (c4>0 here)
    unsigned int cum = excl; int fs = 4*lane;
    for (int ss=3; ss>=0; ss--){
      unsigned int c = scC[4*lane+ss];
      if (cum + c >= target){ fs = 4*lane+ss; break; }
      cum += c;
    }
    for (int bin=fs*bps+bps-1; bin>=fs*bps; bin--){
      unsigned int c = binsLDS[bin];
      if (cum + c >= target){ *sTie = bin; *sR = (int)(target - cum); break; }
      cum += c;
    }
  }
}

// ---------------------------------------------------------------------------
// K2: one block per group. Load hist1, find tie1; one pass over NEGPAT for
// above-sum (registers) + level-2 LDS hist of the tie bin; find tie2;
// finalize group losses and atomicAdd the 4 outputs.
// ---------------------------------------------------------------------------
__global__ __launch_bounds__(1024) void k_select(unsigned int* __restrict__ ws,
                                                 float* __restrict__ out){
  const int g = blockIdx.x, tid = threadIdx.x;
  const int s = g>>5, bIm = g&31;
  const int HW = (s==0)?16384 : (s==1)?4096 : 1024;
  const int N4 = (3*HW)>>2;
  const int patBase = (s==0)?0 : (s==1)?PB1 : PB2;
  const uint4* np = (const uint4*)(ws + WS_NEGPAT + patBase + (size_t)bIm*3*HW);
  float* wf = (float*)ws;

  __shared__ unsigned int h1c[2048];
  __shared__ unsigned int h2c[4096];
  __shared__ float        h2s[4096];
  __shared__ unsigned int scC[256];
  __shared__ int sTie1, sR1, sTie2, sR2;
  __shared__ float sRedA[16], sRedB[16];

  const int pos  = (int)ws[WS_ACC_POS+g];
  const int negc = (int)ws[WS_ACC_NEG+g];
  const int k = min(3*pos, negc);
  float selSum = 0.f;

  if (k > 0){
    h1c[tid]      = ws[WS_HIST1 + g*2048 + tid];
    h1c[tid+1024] = ws[WS_HIST1 + g*2048 + tid+1024];
    #pragma unroll
    for (int i=0;i<4;i++){ h2c[tid+i*1024]=0u; h2s[tid+i*1024]=0.f; }
    __syncthreads();
    if (tid < 256){
      unsigned int sum=0;
      #pragma unroll
      for (int i=0;i<8;i++) sum += h1c[tid*8+i];
      scC[tid]=sum;
    }
    __syncthreads();
    if (tid < 64) wave_suffix_find(h1c, scC, 8, (unsigned)k, &sTie1, &sR1, tid);
    __syncthreads();
    const int tie1 = sTie1;

    float localAbove = 0.f;
    for (int i=tid; i<N4; i+=1024){
      const uint4 v = np[i];
      unsigned int u4[4] = {v.x, v.y, v.z, v.w};
      #pragma unroll
      for (int j=0;j<4;j++){
        const unsigned int u = u4[j];
        if (u != 0xFFFFFFFFu){
          const int bin = (int)(u>>20);
          if (bin > tie1) localAbove += __uint_as_float(u);
          else if (bin == tie1){
            const int b2 = (int)((u>>8)&0xFFFu);
            atomicAdd(&h2c[b2], 1u);
            atomicAdd(&h2s[b2], __uint_as_float(u));
          }
        }
      }
    }
    #pragma unroll
    for (int o=32;o;o>>=1) localAbove += __shfl_down(localAbove,o,64);
    if ((tid&63)==0) sRedA[tid>>6] = localAbove;
    __syncthreads();                       // h2 atomics + sRedA complete
    if (tid < 256){
      unsigned int sum=0;
      #pragma unroll
      for (int i=0;i<16;i++) sum += h2c[tid*16+i];
      scC[tid]=sum;
    }
    __syncthreads();
    if (tid < 64) wave_suffix_find(h2c, scC, 16, (unsigned)sR1, &sTie2, &sR2, tid);
    __syncthreads();
    const int tie2 = sTie2;
    float l2 = 0.f;
    #pragma unroll
    for (int i=0;i<4;i++){
      const int bin = tid*4+i;
      if (bin > tie2) l2 += h2s[bin];
    }
    #pragma unroll
    for (int o=32;o;o>>=1) l2 += __shfl_down(l2,o,64);
    if ((tid&63)==0) sRedB[tid>>6] = l2;
    __syncthreads();
    if (tid==0){
      float above=0.f, acc2=0.f;
      #pragma unroll
      for (int i=0;i<16;i++){ above += sRedA[i]; acc2 += sRedB[i]; }
      const float T = __uint_as_float(((unsigned)sTie1<<20)|((unsigned)sTie2<<8));
      selSum = above + acc2 + (float)sR2 * T;
    }
  }
  if (tid==0){
    const int cObj = pos + k;
    const float lo = (cObj>0) ? (wf[WS_ACC_OBJ+g]+selSum)/(float)cObj : 0.f;
    const float lc = (pos>0)  ? wf[WS_ACC_CLS+g]/(float)pos           : 0.f;
    const float ll = (pos>0)  ? wf[WS_ACC_LOC+g]/(float)(4*pos)       : 0.f;
    const float invB = 1.f/32.f;
    atomicAdd(out+0, (lo + lc + 2.f*ll)*invB);
    atomicAdd(out+1, lo*invB);
    atomicAdd(out+2, lc*invB);
    atomicAdd(out+3, ll*invB);
  }
}

// ---------------------------------------------------------------------------
extern "C" void kernel_launch(void* const* d_in, const int* in_sizes, int n_in,
                              void* d_out, int out_size, void* d_ws, size_t ws_size,
                              hipStream_t stream){
  if (ws_size < (size_t)WS_TOTAL_U32*4) return;   // defensive
  const float* p0  = (const float*)d_in[0];
  const float* p1  = (const float*)d_in[1];
  const float* p2  = (const float*)d_in[2];
  const float* gtb = (const float*)d_in[6];
  const int*   gtl = (const int*)d_in[7];
  unsigned int* ws = (unsigned int*)d_ws;
  float* out = (float*)d_out;

  hipMemsetAsync(d_ws, 0, (size_t)WS_NEGPAT*4, stream);   // accums + hist1
  hipMemsetAsync(d_out, 0, 4*sizeof(float), stream);

  hipLaunchKernelGGL(k_main,   dim3(2688), dim3(256),  0, stream, p0,p1,p2,gtb,gtl,ws);
  hipLaunchKernelGGL(k_select, dim3(96),   dim3(1024), 0, stream, ws, out);
}